// Round 2
// baseline (111.884 us; speedup 1.0000x reference)
//
#include <hip/hip_runtime.h>
#include <hip/hip_bf16.h>
#include <stdint.h>

#define BN 8192
#define DK 256
#define JTILES 16                       // j-tiles of 128 per block (2048/128)
#define KLOG2E_T 20.609929155556617f    // log2(e)/0.07
#define INV_T 14.285714285714286f       // 1/0.07
#define NEGINF (-3.0e38f)

typedef short vshort8 __attribute__((ext_vector_type(8)));
typedef float vfloat4 __attribute__((ext_vector_type(4)));

__device__ __forceinline__ void gload16(const void* g, void* lds) {
  __builtin_amdgcn_global_load_lds(
      (const __attribute__((address_space(1))) unsigned int*)g,
      (__attribute__((address_space(3))) unsigned int*)lds, 16, 0, 0);
}

// ---------------- prep: fp32 -> bf16, pack keys, build key-chains ----------------
__global__ __launch_bounds__(256) void prep_kernel(
    const float* __restrict__ P, const int* __restrict__ aff,
    const int* __restrict__ inst, ushort* __restrict__ Pb,
    int* __restrict__ keys, int* __restrict__ head, int* __restrict__ nxt,
    int* __restrict__ cntA) {
  int g = blockIdx.x * 256 + threadIdx.x;   // 524288 threads, 1 float4 each
  float4 f = ((const float4*)P)[g];
  ushort4 h;
  __hip_bfloat16 b;
  b = __float2bfloat16(f.x); h.x = __builtin_bit_cast(unsigned short, b);
  b = __float2bfloat16(f.y); h.y = __builtin_bit_cast(unsigned short, b);
  b = __float2bfloat16(f.z); h.z = __builtin_bit_cast(unsigned short, b);
  b = __float2bfloat16(f.w); h.w = __builtin_bit_cast(unsigned short, b);
  ((ushort4*)Pb)[g] = h;
  if (g < BN) {
    int a = aff[g];
    int k = (a << 12) | inst[g];
    keys[g] = k;
    nxt[g] = atomicExch(&head[k], g);   // build per-key linked list
    atomicAdd(&cntA[a], 1);
  }
}

// ---------------- per-affordance-class row sums G[16][256] ----------------
__global__ __launch_bounds__(256) void accum_g(
    const float* __restrict__ P, const int* __restrict__ aff,
    float* __restrict__ G) {
  __shared__ float Gl[16 * 256];
  const int t = threadIdx.x;
#pragma unroll
  for (int a = 0; a < 16; ++a) Gl[a * 256 + t] = 0.f;
  const int r0 = blockIdx.x * 256;
  for (int r = r0; r < r0 + 256; ++r) {
    float v = P[(size_t)r * 256 + t];
    int a = aff[r];
    Gl[a * 256 + t] += v;     // thread-private column t: no races
  }
#pragma unroll
  for (int a = 0; a < 16; ++a) atomicAdd(&G[a * 256 + t], Gl[a * 256 + t]);
}

// ---------------- fused GEMM + online LSE (max/exp only) ----------------
__global__ __launch_bounds__(512, 4) void fused_kernel(
    const ushort* __restrict__ Pb, float2* __restrict__ stats) {
  __shared__ __align__(16) ushort Abuf[4 * 64 * 64];    // 32KB, full K resident
  __shared__ __align__(16) ushort Bbuf[2][128 * 64];    // 2 x 16KB dbuf

  const int tid = threadIdx.x;
  const int w = tid >> 6;       // wave 0..7
  const int l = tid & 63;
  const int q = l >> 4;         // 0..3
  const int li = l & 15;
  const int iw = w >> 1;        // 0..3 : i-wave (16 rows each)
  const int jw = w & 1;         // 0..1 : j-wave (64 cols each)

  const int bid = blockIdx.x;
  const int chunk = (bid & 7) >> 1;                 // 0..3 (XCD pairs share chunk)
  const int itile = ((bid >> 3) << 1) + (bid & 1);  // 0..127
  const int ibase = itile * 64;
  const int jcbase = chunk * 2048;

  const int gi = ibase + iw * 16 + li;

  // staging: thread t writes 16B LDS block (t&7) of row (t>>3), pre-swizzled src
  const int srow = tid >> 3;                        // 0..63
  const size_t srcrow = (size_t)srow * (DK * 2);
  const int sboff = ((tid & 7) ^ (srow & 7)) * 16;
  const int dst16 = tid * 16;

  // ---- prologue: stage full A (64 rows x 256 k, 4 ks-bufs) ----
  const char* gA = (const char*)(Pb + (size_t)ibase * DK);
#pragma unroll
  for (int ks = 0; ks < 4; ++ks)
    gload16(gA + srcrow + ks * 128 + sboff, (char*)Abuf + ks * 8192 + dst16);
  // stage B(jt=0, ks=0): 128 rows x 64 k
  {
    const char* gB = (const char*)(Pb + (size_t)jcbase * DK);
    gload16(gB + srcrow + sboff, (char*)&Bbuf[0][0] + dst16);
    gload16(gB + srcrow + (size_t)64 * (DK * 2) + sboff,
            (char*)&Bbuf[0][0] + 8192 + dst16);
  }
  __syncthreads();

  // operand read offsets (swizzled): row&7 == li&7 for all our rows
  const int rowAb = (iw * 16 + li) * 128;
  const int rowBb = (jw * 64 + li) * 128;
  const int swz0 = ((0 * 4 + q) ^ (li & 7)) * 16;
  const int swz1 = ((1 * 4 + q) ^ (li & 7)) * 16;
  const int iwb = ibase + iw * 16;

  float m = NEGINF, sA = 0.f, sB = 0.f;

  for (int jt = 0; jt < JTILES; ++jt) {
    const int jtb = jcbase + jt * 128;
    const char* gBj = (const char*)(Pb + (size_t)jtb * DK);
    vfloat4 acc[4];
#pragma unroll
    for (int fj = 0; fj < 4; ++fj) acc[fj] = (vfloat4){0.f, 0.f, 0.f, 0.f};

#pragma unroll
    for (int ks = 0; ks < 4; ++ks) {
      if (ks < 3) {  // prefetch next k-step of B
        char* dst = (char*)&Bbuf[(ks + 1) & 1][0] + dst16;
        gload16(gBj + srcrow + (ks + 1) * 128 + sboff, dst);
        gload16(gBj + srcrow + (size_t)64 * (DK * 2) + (ks + 1) * 128 + sboff,
                dst + 8192);
      }
      const char* As = (const char*)Abuf + ks * 8192;
      const char* Bs = (const char*)&Bbuf[ks & 1][0];
#pragma unroll
      for (int kk = 0; kk < 2; ++kk) {
        const int colo = kk ? swz1 : swz0;
        vshort8 i0 = *(const vshort8*)(As + rowAb + colo);
#pragma unroll
        for (int fj = 0; fj < 4; ++fj) {
          vshort8 jv = *(const vshort8*)(Bs + rowBb + fj * 2048 + colo);
          acc[fj] = __builtin_amdgcn_mfma_f32_16x16x32_bf16(jv, i0, acc[fj], 0, 0, 0);
        }
      }
      if (ks < 3) __syncthreads();
    }

    // prefetch next tile's first B chunk, hidden under epilogue
    if (jt + 1 < JTILES) {
      const char* gB = gBj + 128 * (DK * 2);
      char* dst = (char*)&Bbuf[0][0] + dst16;
      gload16(gB + srcrow + sboff, dst);
      gload16(gB + srcrow + (size_t)64 * (DK * 2) + sboff, dst + 8192);
    }

    // ---- epilogue: self-mask, tile max, online exp-sum ----
    float tmax = NEGINF;
#pragma unroll
    for (int fj = 0; fj < 4; ++fj) {
      const bool dia = (jtb + jw * 64 + fj * 16) == iwb;
#pragma unroll
      for (int r = 0; r < 4; ++r) {
        float v = acc[fj][r];
        if (dia && (q * 4 + r) == li) v = NEGINF;
        acc[fj][r] = v;
        tmax = fmaxf(tmax, v);
      }
    }
    tmax = fmaxf(tmax, __shfl_xor(tmax, 16));
    tmax = fmaxf(tmax, __shfl_xor(tmax, 32));
    const float mn = fmaxf(m, tmax);
    const float rs = exp2f((m - mn) * KLOG2E_T);
    sA *= rs;
    sB *= rs;
    m = mn;
    const float rc = -mn * KLOG2E_T;
#pragma unroll
    for (int fj = 0; fj < 4; ++fj) {
      sA += exp2f(fmaf(acc[fj][0], KLOG2E_T, rc));
      sB += exp2f(fmaf(acc[fj][1], KLOG2E_T, rc));
      sA += exp2f(fmaf(acc[fj][2], KLOG2E_T, rc));
      sB += exp2f(fmaf(acc[fj][3], KLOG2E_T, rc));
    }
    __syncthreads();
  }

  // combine the 4 col-partitions (lanes l, l^16, l^32, l^48)
  float s = sA + sB;
  s += __shfl_xor(s, 16);
  s += __shfl_xor(s, 32);
  if (l < 16) {
    const int slot = chunk * 2 + jw;
    stats[(size_t)slot * BN + gi] = make_float2(m, s);
  }
}

// ---------------- per-row: merge 8 lse-partials + algebraic pos-sums ----------------
__global__ __launch_bounds__(256) void final_rows(
    const float2* __restrict__ stats, const float* __restrict__ P,
    const float* __restrict__ G, const int* __restrict__ keys,
    const int* __restrict__ head, const int* __restrict__ nxt,
    const int* __restrict__ cntA, float2* __restrict__ part) {
  const int t = threadIdx.x;
  const int rloc = t >> 6;    // 0..3
  const int lane = t & 63;
  const int i = blockIdx.x * 4 + rloc;

  // merge 8 (m,s) partials via 8-lane shuffle tree (all lanes redundant)
  float2 st = stats[(size_t)(lane & 7) * BN + i];
  float mm = st.x, ss = st.y;
#pragma unroll
  for (int off = 1; off < 8; off <<= 1) {
    float mo = __shfl_xor(mm, off);
    float so = __shfl_xor(ss, off);
    float M = fmaxf(mm, mo);
    ss = ss * exp2f((mm - M) * KLOG2E_T) + so * exp2f((mo - M) * KLOG2E_T);
    mm = M;
  }
  const float lse = logf(ss) + mm * INV_T;

  // dotA - S2 via exact fp32
  const int key = keys[i];
  const int a = key >> 12;
  float4 p4 = ((const float4*)(P + (size_t)i * 256))[lane];
  float4 g4 = ((const float4*)(G + a * 256))[lane];
  float acc = p4.x * g4.x + p4.y * g4.y + p4.z * g4.z + p4.w * g4.w;
  int cnt = 0;
  int j = head[key];
  while (j >= 0) {                       // same-key rows (includes self)
    float4 q4 = ((const float4*)(P + (size_t)j * 256))[lane];
    acc -= p4.x * q4.x + p4.y * q4.y + p4.z * q4.z + p4.w * q4.w;
    cnt++;
    j = nxt[j];
  }
#pragma unroll
  for (int off = 1; off < 64; off <<= 1) acc += __shfl_xor(acc, off);
  const float pc = (float)(cntA[a] - cnt);
  const float contrib = pc * lse - acc * INV_T;

  __shared__ float cs[4], ps[4];
  if (lane == 0) { cs[rloc] = contrib; ps[rloc] = pc; }
  __syncthreads();
  if (t == 0)
    part[blockIdx.x] = make_float2(cs[0] + cs[1] + cs[2] + cs[3],
                                   ps[0] + ps[1] + ps[2] + ps[3]);
}

__global__ void finalize(const float2* __restrict__ part, float* __restrict__ out) {
  const int t = threadIdx.x;   // 256 threads
  float c = 0.f, p = 0.f;
  for (int k = t; k < 2048; k += 256) {
    float2 v = part[k];
    c += v.x;
    p += v.y;
  }
#pragma unroll
  for (int off = 1; off < 64; off <<= 1) {
    c += __shfl_xor(c, off);
    p += __shfl_xor(p, off);
  }
  __shared__ float cs[4], ps[4];
  if ((t & 63) == 0) { cs[t >> 6] = c; ps[t >> 6] = p; }
  __syncthreads();
  if (t == 0) {
    c = cs[0] + cs[1] + cs[2] + cs[3];
    p = ps[0] + ps[1] + ps[2] + ps[3];
    out[0] = (p > 0.f) ? (c / p) : 0.f;
  }
}

extern "C" void kernel_launch(void* const* d_in, const int* in_sizes, int n_in,
                              void* d_out, int out_size, void* d_ws, size_t ws_size,
                              hipStream_t stream) {
  const float* P = (const float*)d_in[0];
  const int* aff = (const int*)d_in[1];
  const int* inst = (const int*)d_in[2];
  char* ws = (char*)d_ws;
  ushort* Pb   = (ushort*)(ws);                       // 4 MB
  int*    keys = (int*)(ws + 4194304);                // 32 KB
  int*    head = (int*)(ws + 4227072);                // 256 KB (65536 bins)
  int*    nxt  = (int*)(ws + 4489216);                // 32 KB
  float*  G    = (float*)(ws + 4521984);              // 16 KB (16x256)
  int*    cntA = (int*)(ws + 4538368);                // 64 B
  float2* stats = (float2*)(ws + 4538432);            // 512 KB (8 x 8192 x 8B)
  float2* part = (float2*)(ws + 5062720);             // 16 KB
  float* out = (float*)d_out;

  hipMemsetAsync(head, 0xFF, 65536 * 4, stream);      // head = -1
  hipMemsetAsync(G, 0, 4096 * 4 + 64, stream);        // G and cntA = 0
  prep_kernel<<<2048, 256, 0, stream>>>(P, aff, inst, Pb, keys, head, nxt, cntA);
  accum_g<<<32, 256, 0, stream>>>(P, aff, G);
  fused_kernel<<<512, 512, 0, stream>>>(Pb, stats);
  final_rows<<<2048, 256, 0, stream>>>(stats, P, G, keys, head, nxt, cntA, part);
  finalize<<<1, 256, 0, stream>>>(part, out);
}